// Round 17
// baseline (224.294 us; speedup 1.0000x reference)
//
#include <hip/hip_runtime.h>

typedef __bf16 bf16x8 __attribute__((ext_vector_type(8)));
typedef float  f32x4  __attribute__((ext_vector_type(4)));

#define AS1 __attribute__((address_space(1)))
#define AS3 __attribute__((address_space(3)))

__device__ __forceinline__ float bf2f(ushort u) {
    union { unsigned int i; float f; } v; v.i = ((unsigned int)u) << 16; return v.f;
}
__device__ __forceinline__ ushort f2bf(float f) {
    union { float f; unsigned int i; } v; v.f = f;
    unsigned int i = v.i;
    unsigned int r = i + 0x7FFFu + ((i >> 16) & 1u);   // RNE
    return (ushort)(r >> 16);
}
__device__ __forceinline__ float bflo(unsigned int u) { return bf2f((ushort)(u & 0xFFFFu)); }
__device__ __forceinline__ float bfhi(unsigned int u) { return bf2f((ushort)(u >> 16)); }
__device__ __forceinline__ float gelu_f(float v) {
    return 0.5f * v * (1.f + erff(v * 0.70710678118654752f));
}

// wave-level inline dtype sniff: 1 = bf16 inputs, 0 = f32
__device__ __forceinline__ bool sniff_inline(const ushort* __restrict__ x) {
    const int lane = threadIdx.x & 63;
    int cnt = 0;
    #pragma unroll
    for (int r = 0; r < 4; r++) {
        const ushort u = x[lane + r * 64];
        const int e = (u >> 7) & 0xFF;
        if ((u & 0x7FFF) == 0 || (e >= 112 && e <= 141)) cnt++;
    }
    #pragma unroll
    for (int o = 32; o > 0; o >>= 1) cnt += __shfl_xor(cnt, o);
    return cnt >= 224;
}

// ---------------------------------------------------------------------------
// canonicalize all inputs into packed bf16 region; also writes xpw_pad [64,512]
// ---------------------------------------------------------------------------
struct CanonArgs {
    const void* src[20];
    int off[20];
    int total;
};

__launch_bounds__(256)
__global__ void canon_k(CanonArgs a, ushort* __restrict__ dst, ushort* __restrict__ xpw_pad,
                        const ushort* __restrict__ sniffx)
{
    const int i = blockIdx.x * 256 + threadIdx.x;
    if (i >= a.total) {
        const int j = i - a.total;
        if (j < 8192) xpw_pad[24576 + j] = 0;   // pad rows 48..63
        return;
    }
    const bool fl = sniff_inline(sniffx);
    int s = 0;
    #pragma unroll
    for (int t = 1; t < 20; t++) if (i >= a.off[t]) s = t;
    const int li = i - a.off[s];
    ushort v;
    if (fl) v = ((const ushort*)a.src[s])[li];
    else    v = f2bf(((const float*)a.src[s])[li]);
    dst[i] = v;
    if (s == 5) xpw_pad[li] = v;                // xpw rows 0..47
}

// ---------------------------------------------------------------------------
// GEMM vs B^T weights, BK=64 single-buffer:
// C[M,N] = A[M,K](lda) @ W[N,K]^T + bias
// EPI: 0 = bias, 1 = bias+gelu, 2 = bias + bf16 residual (stride N),
//      3 = bias, then silu for gn >= 512 (pre-gated z-half for in_proj).
// OUTF: write float instead of bf16.
// LDS XOR-swizzle (chunk ^= row&7, 16B chunks) on both staging source and
// ds_read side keeps the 128B row stride conflict-free. BM in {32,64}.
// ---------------------------------------------------------------------------
template<int BM, int BN, int EPI, bool OUTF>
__launch_bounds__(256, 4)
__global__ void gemm_bt(const ushort* __restrict__ A, int lda, const ushort* __restrict__ W,
                        const ushort* __restrict__ bias, const ushort* __restrict__ resid,
                        void* __restrict__ Cb, int N, int K)
{
    constexpr int WNT = BN / 32;
    __shared__ __align__(16) ushort As[BM * 64];
    __shared__ __align__(16) ushort Bs[BN * 64];
    const int tid  = threadIdx.x;
    const int wave = tid >> 6;
    const int lane = tid & 63;
    const int m0 = blockIdx.x * BM;
    const int n0 = blockIdx.y * BN;
    const int wm = (wave >> 1) * (BM / 2);
    const int wn = (wave & 1) * (BN / 2);
    const int lrow = lane & 15;
    const int quad = lane >> 4;
    // staging decomposition: 8 lanes per 64-elem row, 8 rows per inst
    const int rsub = lane >> 3;                    // 0..7 (row within inst)
    const int ksub = (lane & 7) ^ rsub;            // swizzled k-chunk for linear LDS dest

    constexpr int WMR = (BM == 32) ? 1 : BM / 32;  // row-fragment repeats per wave
    f32x4 acc[WMR][WNT];
    #pragma unroll
    for (int i = 0; i < WMR; i++)
        #pragma unroll
        for (int j = 0; j < WNT; j++)
            #pragma unroll
            for (int r = 0; r < 4; r++) acc[i][j][r] = 0.f;

    for (int k0 = 0; k0 < K; k0 += 64) {
        #pragma unroll
        for (int t = 0; t < BM / 32; t++) {        // A insts = BM/8, /4 waves
            const int inst = t * 4 + wave;
            const int row  = inst * 8 + rsub;
            const ushort* gp = A + (size_t)(m0 + row) * lda + (k0 + ksub * 8);
            __builtin_amdgcn_global_load_lds((AS1 void*)(void*)gp,
                                             (AS3 void*)(As + inst * 512), 16, 0, 0);
        }
        #pragma unroll
        for (int t = 0; t < BN / 32; t++) {        // B insts = BN/8, /4 waves
            const int inst = t * 4 + wave;
            const int row  = inst * 8 + rsub;
            const ushort* gp = W + (size_t)(n0 + row) * K + (k0 + ksub * 8);
            __builtin_amdgcn_global_load_lds((AS1 void*)(void*)gp,
                                             (AS3 void*)(Bs + inst * 512), 16, 0, 0);
        }
        __syncthreads();
        #pragma unroll
        for (int kk = 0; kk < 64; kk += 32) {
            bf16x8 afr[WMR], bfr[WNT];
            #pragma unroll
            for (int i = 0; i < WMR; i++) {
                const int r = wm + i * 16 + lrow;
                const int ch = (kk >> 3) + quad;
                afr[i] = *(const bf16x8*)&As[r * 64 + ((ch ^ (r & 7)) << 3)];
            }
            #pragma unroll
            for (int j = 0; j < WNT; j++) {
                const int r = wn + j * 16 + lrow;
                const int ch = (kk >> 3) + quad;
                bfr[j] = *(const bf16x8*)&Bs[r * 64 + ((ch ^ (r & 7)) << 3)];
            }
            #pragma unroll
            for (int i = 0; i < WMR; i++)
                #pragma unroll
                for (int j = 0; j < WNT; j++)
                    acc[i][j] = __builtin_amdgcn_mfma_f32_16x16x32_bf16(afr[i], bfr[j], acc[i][j], 0, 0, 0);
        }
        __syncthreads();
    }

    #pragma unroll
    for (int i = 0; i < WMR; i++) {
        const int gm = m0 + wm + i * 16 + quad * 4;
        #pragma unroll
        for (int j = 0; j < WNT; j++) {
            const int gn = n0 + wn + j * 16 + lrow;
            const float bv = bf2f(bias[gn]);
            #pragma unroll
            for (int r = 0; r < 4; r++) {
                float v = acc[i][j][r] + bv;
                if (EPI == 1) v = gelu_f(v);
                if (EPI == 2) v += bf2f(resid[(size_t)(gm + r) * N + gn]);
                if (EPI == 3) { if (gn >= 512) v = v / (1.f + __expf(-v)); }
                if (OUTF) ((float*)Cb)[(size_t)(gm + r) * N + gn] = v;
                else      ((ushort*)Cb)[(size_t)(gm + r) * N + gn] = f2bf(v);
            }
        }
    }
}

// ---------------------------------------------------------------------------
// LN1: row-LN over 256 cols of y1pre (f32); writes y1b bf16 + y1f f32
// (y1f in-place over y1pre). grid 1024 x 512.
// ---------------------------------------------------------------------------
__launch_bounds__(512)
__global__ void ln1_k(float* __restrict__ y1pre, const ushort* __restrict__ g1,
                      const ushort* __restrict__ b1, ushort* __restrict__ y1b)
{
    const int tid  = threadIdx.x;
    const int wave = tid >> 6;
    const int lane = tid & 63;
    const int row  = blockIdx.x * 8 + wave;
    const int col0 = lane * 4;

    const f32x4 a = *(const f32x4*)&y1pre[(size_t)row * 256 + col0];
    float S = 0.f, Q = 0.f;
    #pragma unroll
    for (int k = 0; k < 4; k++) { S += a[k]; Q += a[k] * a[k]; }
    #pragma unroll
    for (int o = 32; o > 0; o >>= 1) {
        S += __shfl_xor(S, o);
        Q += __shfl_xor(Q, o);
    }
    const float mean = S * (1.f / 256.f);
    const float var  = Q * (1.f / 256.f) - mean * mean;
    const float rs   = rsqrtf(var + 1e-5f);

    float of[4];
    ushort ob[4];
    #pragma unroll
    for (int k = 0; k < 4; k++) {
        of[k] = (a[k] - mean) * rs * bf2f(g1[col0 + k]) + bf2f(b1[col0 + k]);
        ob[k] = f2bf(of[k]);
    }
    *(f32x4*)&y1pre[(size_t)row * 256 + col0] = *(f32x4*)&of[0];   // y1f in-place
    *(ushort4*)&y1b[(size_t)row * 256 + col0] = *(ushort4*)&ob[0];
}

// ---------------------------------------------------------------------------
// FUSED conv+SiLU + xdbl projection + scan pass 1. grid (128c, 4b) x 512.
// xc global write after scan1 (stores retire in kernel-end drain).
// ---------------------------------------------------------------------------
__launch_bounds__(512, 2)
__global__ void convscan1_k(const ushort* __restrict__ xz, const ushort* __restrict__ cw,
                            const ushort* __restrict__ cb, const ushort* __restrict__ xpw_pad,
                            const ushort* __restrict__ dtw, const ushort* __restrict__ dtb,
                            const ushort* __restrict__ Alog,
                            ushort* __restrict__ xc, float* __restrict__ xdbl,
                            float* __restrict__ summh, float* __restrict__ sdtb)
{
    __shared__ __align__(16) ushort xcs[16 * 520];
    __shared__ float XD[16 * 48];
    const int tid  = threadIdx.x;
    const int wave = tid >> 6;
    const int lane = tid & 63;
    const int lrow = lane & 15;
    const int quad = lane >> 4;
    const int c = blockIdx.x, b = blockIdx.y;
    const int t0 = b * 2048 + c * 16;

    // ---- conv + silu -> xcs ----
    {
        const int d8 = (tid & 63) * 8;
        ushort wl[32];
        *(uint4*)&wl[0]  = *(const uint4*)&cw[d8 * 4];
        *(uint4*)&wl[8]  = *(const uint4*)&cw[d8 * 4 + 8];
        *(uint4*)&wl[16] = *(const uint4*)&cw[d8 * 4 + 16];
        *(uint4*)&wl[24] = *(const uint4*)&cw[d8 * 4 + 24];
        ushort bl[8];
        *(uint4*)&bl[0] = *(const uint4*)&cb[d8];
        #pragma unroll
        for (int it = 0; it < 2; it++) {
            const int trow = it * 8 + wave;
            const int t = t0 + trow;
            const int l = t & 2047;
            float acc[8];
            #pragma unroll
            for (int j = 0; j < 8; j++) acc[j] = bf2f(bl[j]);
            #pragma unroll
            for (int k = 0; k < 4; k++) {
                const int ls = l - 3 + k;
                if (ls >= 0) {
                    ushort xl[8];
                    *(uint4*)&xl[0] = *(const uint4*)&xz[(size_t)(t - 3 + k) * 1024 + d8];
                    #pragma unroll
                    for (int j = 0; j < 8; j++) acc[j] += bf2f(xl[j]) * bf2f(wl[j * 4 + k]);
                }
            }
            ushort ol[8];
            #pragma unroll
            for (int j = 0; j < 8; j++) {
                const float s = acc[j] / (1.f + __expf(-acc[j]));
                ol[j] = f2bf(s);
            }
            *(uint4*)&xcs[trow * 520 + d8] = *(uint4*)&ol[0];
        }
    }
    __syncthreads();

    // ---- xdbl = xcs @ xpw_pad^T: M=16, N=48, K=512; waves 0..2 fill XD ----
    if (wave < 3) {
        const int nt = wave;
        const ushort* bptr = xpw_pad + (size_t)(nt * 16 + lrow) * 512 + quad * 8;
        f32x4 acc = {0.f, 0.f, 0.f, 0.f};
        #pragma unroll
        for (int hh = 0; hh < 2; hh++) {
            bf16x8 Bv[8];
            #pragma unroll
            for (int s = 0; s < 8; s++)
                Bv[s] = *(const bf16x8*)(bptr + hh * 256 + s * 32);
            #pragma unroll
            for (int s = 0; s < 8; s++) {
                const bf16x8 afr = *(const bf16x8*)&xcs[lrow * 520 + hh * 256 + s * 32 + quad * 8];
                acc = __builtin_amdgcn_mfma_f32_16x16x32_bf16(afr, Bv[s], acc, 0, 0, 0);
            }
        }
        const int col = nt * 16 + lrow;
        if (col < 48) {
            #pragma unroll
            for (int r = 0; r < 4; r++) {
                const int row = quad * 4 + r;
                XD[row * 48 + col] = acc[r];
                xdbl[(size_t)(t0 + row) * 64 + col] = acc[r];
            }
        }
    }
    __syncthreads();

    // ---- scan pass 1: thread owns d = tid; xi and XD from LDS ----
    {
        const int d = tid;
        const uint4 w0 = *(const uint4*)&dtw[d * 16];
        const uint4 w1 = *(const uint4*)&dtw[d * 16 + 8];
        const float wd[16] = { bflo(w0.x), bfhi(w0.x), bflo(w0.y), bfhi(w0.y),
                               bflo(w0.z), bfhi(w0.z), bflo(w0.w), bfhi(w0.w),
                               bflo(w1.x), bfhi(w1.x), bflo(w1.y), bfhi(w1.y),
                               bflo(w1.z), bfhi(w1.z), bflo(w1.w), bfhi(w1.w) };
        const uint4 a0 = *(const uint4*)&Alog[d * 16];
        const uint4 a1 = *(const uint4*)&Alog[d * 16 + 8];
        const float al[16] = { bflo(a0.x), bfhi(a0.x), bflo(a0.y), bfhi(a0.y),
                               bflo(a0.z), bfhi(a0.z), bflo(a0.w), bfhi(a0.w),
                               bflo(a1.x), bfhi(a1.x), bflo(a1.y), bfhi(a1.y),
                               bflo(a1.z), bfhi(a1.z), bflo(a1.w), bfhi(a1.w) };
        const float dtbv = bf2f(dtb[d]);
        float A[16], h[16];
        #pragma unroll
        for (int n = 0; n < 16; n++) { A[n] = -__expf(al[n]); h[n] = 0.f; }
        float sdt = 0.f;
        for (int i = 0; i < 16; i++) {
            const float* Xr = &XD[i * 48];
            float s0 = dtbv, s1 = 0.f, s2 = 0.f, s3 = 0.f;
            #pragma unroll
            for (int k = 0; k < 16; k += 4) {
                s0 += Xr[k]     * wd[k];
                s1 += Xr[k + 1] * wd[k + 1];
                s2 += Xr[k + 2] * wd[k + 2];
                s3 += Xr[k + 3] * wd[k + 3];
            }
            const float s = (s0 + s1) + (s2 + s3);
            const float dtv = (s > 15.f) ? s : __logf(1.f + __expf(s));
            const float xiv = bf2f(xcs[i * 520 + d]);
            const float dx = dtv * xiv;
            sdt += dtv;
            #pragma unroll
            for (int n = 0; n < 16; n++) {
                const float da = __expf(dtv * A[n]);
                h[n] = da * h[n] + dx * Xr[16 + n];
            }
        }
        const size_t bh = ((size_t)(b * 128 + c) * 16) * 512 + d;
        #pragma unroll
        for (int n = 0; n < 16; n++) summh[bh + (size_t)n * 512] = h[n];
        sdtb[(size_t)(b * 128 + c) * 512 + d] = sdt;
    }

    // ---- write xc to global (after scan1; retires in kernel-end drain) ----
    {
        const int row = tid >> 5;
        const int col = (tid & 31) * 16;
        *(uint4*)&xc[(size_t)(t0 + row) * 512 + col]     = *(const uint4*)&xcs[row * 520 + col];
        *(uint4*)&xc[(size_t)(t0 + row) * 512 + col + 8] = *(const uint4*)&xcs[row * 520 + col + 8];
    }
}

// sequential combine over 128 chunks; recomputes decay p = exp(A[n]*sdt);
// overwrites h-slot with exclusive-prefix h_in. grid 256 x 128 (b,n,dq).
__launch_bounds__(128)
__global__ void combine_k(float* __restrict__ summh, const float* __restrict__ sdtb,
                          const ushort* __restrict__ Alog)
{
    const int b  = blockIdx.x >> 6;
    const int n  = (blockIdx.x >> 2) & 15;
    const int dq = blockIdx.x & 3;
    const int d  = dq * 128 + threadIdx.x;
    const float An = -__expf(bf2f(Alog[d * 16 + n]));
    float h = 0.f;
    #pragma unroll
    for (int q = 0; q < 4; q++) {
        float p[32], hl[32], ho[32];
        #pragma unroll
        for (int c2 = 0; c2 < 32; c2++) {
            const int cc = q * 32 + c2;
            hl[c2] = summh[((size_t)(b * 128 + cc) * 16 + n) * 512 + d];
            p[c2]  = __expf(An * sdtb[(size_t)(b * 128 + cc) * 512 + d]);
        }
        #pragma unroll
        for (int c2 = 0; c2 < 32; c2++) {
            ho[c2] = h;
            h = p[c2] * h + hl[c2];
        }
        #pragma unroll
        for (int c2 = 0; c2 < 32; c2++)
            summh[((size_t)(b * 128 + (q * 32 + c2)) * 16 + n) * 512 + d] = ho[c2];
    }
}

// ---------------------------------------------------------------------------
// scan pass 2: 16-token chunks, d-split x2. grid (128c, 2dh, 4b) x 256.
// reads h_in from summh; z-half of xz is PRE-GATED (silu applied by in_proj)
// so the gate is a single multiply; writes gated y IN-PLACE into xc.
// ---------------------------------------------------------------------------
__launch_bounds__(256)
__global__ void scan2_k(const ushort* __restrict__ xz, ushort* __restrict__ xc,
                        const float* __restrict__ xdbl,
                        const ushort* __restrict__ dtw, const ushort* __restrict__ dtb,
                        const ushort* __restrict__ Alog, const float* __restrict__ summh,
                        const ushort* __restrict__ Dssm)
{
    __shared__ float XD[16 * 48];
    const int tid = threadIdx.x;
    const int c = blockIdx.x, dh = blockIdx.y, b = blockIdx.z;
    const int t0 = b * 2048 + c * 16;
    const int d = dh * 256 + tid;

    for (int e = tid; e < 768; e += 256)
        XD[e] = xdbl[(size_t)(t0 + (e / 48)) * 64 + (e % 48)];
    __syncthreads();

    const uint4 w0 = *(const uint4*)&dtw[d * 16];
    const uint4 w1 = *(const uint4*)&dtw[d * 16 + 8];
    const float wd[16] = { bflo(w0.x), bfhi(w0.x), bflo(w0.y), bfhi(w0.y),
                           bflo(w0.z), bfhi(w0.z), bflo(w0.w), bfhi(w0.w),
                           bflo(w1.x), bfhi(w1.x), bflo(w1.y), bfhi(w1.y),
                           bflo(w1.z), bfhi(w1.z), bflo(w1.w), bfhi(w1.w) };
    const uint4 a0 = *(const uint4*)&Alog[d * 16];
    const uint4 a1 = *(const uint4*)&Alog[d * 16 + 8];
    const float al[16] = { bflo(a0.x), bfhi(a0.x), bflo(a0.y), bfhi(a0.y),
                           bflo(a0.z), bfhi(a0.z), bflo(a0.w), bfhi(a0.w),
                           bflo(a1.x), bfhi(a1.x), bflo(a1.y), bfhi(a1.y),
                           bflo(a1.z), bfhi(a1.z), bflo(a1.w), bfhi(a1.w) };
    const float dtbv = bf2f(dtb[d]);
    float A[16], h[16];
    #pragma unroll
    for (int n = 0; n < 16; n++) A[n] = -__expf(al[n]);
    const size_t bh = ((size_t)(b * 128 + c) * 16) * 512 + d;
    #pragma unroll
    for (int n = 0; n < 16; n++) h[n] = summh[bh + (size_t)n * 512];
    const float Dv = bf2f(Dssm[d]);

    for (int i = 0; i < 16; i++) {
        const int t = t0 + i;
        const float* Xr = &XD[i * 48];
        float s0 = dtbv, s1 = 0.f, s2 = 0.f, s3 = 0.f;
        #pragma unroll
        for (int k = 0; k < 16; k += 4) {
            s0 += Xr[k]     * wd[k];
            s1 += Xr[k + 1] * wd[k + 1];
            s2 += Xr[k + 2] * wd[k + 2];
            s3 += Xr[k + 3] * wd[k + 3];
        }
        const float s = (s0 + s1) + (s2 + s3);
        const float dtv = (s > 15.f) ? s : __logf(1.f + __expf(s));
        const float xiv = bf2f(xc[(size_t)t * 512 + d]);
        const float dx = dtv * xiv;
        float yv0 = 0.f, yv1 = 0.f;
        #pragma unroll
        for (int n = 0; n < 16; n += 2) {
            const float da0 = __expf(dtv * A[n]);
            const float da1 = __expf(dtv * A[n + 1]);
            h[n]     = da0 * h[n]     + dx * Xr[16 + n];
            h[n + 1] = da1 * h[n + 1] + dx * Xr[17 + n];
            yv0 += h[n]     * Xr[32 + n];
            yv1 += h[n + 1] * Xr[33 + n];
        }
        float yv = yv0 + yv1;
        yv += xiv * Dv;
        yv *= bf2f(xz[(size_t)t * 1024 + 512 + d]);   // z pre-gated (silu in in_proj)
        xc[(size_t)t * 512 + d] = f2bf(yv);   // in-place: yg overwrites xi
    }
}

// ---------------------------------------------------------------------------
// final LN2: v = y2g + y1f (gelu already applied by fc2); row-LN over 256;
// dtype-sniffed output.
// ---------------------------------------------------------------------------
__launch_bounds__(512)
__global__ void ln2_k(const float* __restrict__ y2, const float* __restrict__ y1f,
                      const ushort* __restrict__ g2, const ushort* __restrict__ b2,
                      void* __restrict__ dout, const ushort* __restrict__ sniffx)
{
    const int tid  = threadIdx.x;
    const int wave = tid >> 6;
    const int lane = tid & 63;
    const int row  = blockIdx.x * 8 + wave;
    const int col0 = lane * 4;

    const f32x4 a = *(const f32x4*)&y2[(size_t)row * 256 + col0];
    const f32x4 rsd = *(const f32x4*)&y1f[(size_t)row * 256 + col0];
    float v[4];
    float S = 0.f, Q = 0.f;
    #pragma unroll
    for (int k = 0; k < 4; k++) {
        v[k] = a[k] + rsd[k];
        S += v[k];
        Q += v[k] * v[k];
    }
    #pragma unroll
    for (int o = 32; o > 0; o >>= 1) {
        S += __shfl_xor(S, o);
        Q += __shfl_xor(Q, o);
    }
    const float mean = S * (1.f / 256.f);
    const float var  = Q * (1.f / 256.f) - mean * mean;
    const float rs   = rsqrtf(var + 1e-5f);

    const bool fl = sniff_inline(sniffx);
    if (fl) {
        ushort o4[4];
        #pragma unroll
        for (int k = 0; k < 4; k++)
            o4[k] = f2bf((v[k] - mean) * rs * bf2f(g2[col0 + k]) + bf2f(b2[col0 + k]));
        *(ushort4*)((ushort*)dout + (size_t)row * 256 + col0) = *(ushort4*)&o4[0];
    } else {
        float o4[4];
        #pragma unroll
        for (int k = 0; k < 4; k++)
            o4[k] = (v[k] - mean) * rs * bf2f(g2[col0 + k]) + bf2f(b2[col0 + k]);
        *(float4*)((float*)dout + (size_t)row * 256 + col0) = *(float4*)&o4[0];
    }
}

// ---------------------------------------------------------------------------
extern "C" void kernel_launch(void* const* d_in, const int* in_sizes, int n_in,
                              void* d_out, int out_size, void* d_ws, size_t ws_size,
                              hipStream_t stream)
{
    char* ws = (char*)d_ws;
    ushort* canon = (ushort*)(ws + 256);

    static const int coff[20] = {
        0,        2097152,  2359296,  2360320,  2362368,
        2362880,  2387456,  2395648,  2396160,  2404352,
        2404864,  2535936,  2536192,  2536448,  2536704,
        2798848,  2799872,  3062016,  3062272,  3062528 };
    static const int ctot = 3062784;

    CanonArgs ca;
    for (int i = 0; i < 20; i++) { ca.src[i] = d_in[i]; ca.off[i] = coff[i]; }
    ca.total = ctot;

    const ushort* cx   = canon + coff[0];
    const ushort* cipw = canon + coff[1];
    const ushort* cipb = canon + coff[2];
    const ushort* ccw  = canon + coff[3];
    const ushort* ccb  = canon + coff[4];
    const ushort* cdtw = canon + coff[6];
    const ushort* cdtb = canon + coff[7];
    const ushort* calog= canon + coff[8];
    const ushort* cdssm= canon + coff[9];
    const ushort* copw = canon + coff[10];
    const ushort* copb = canon + coff[11];
    const ushort* cln1g= canon + coff[12];
    const ushort* cln1b= canon + coff[13];
    const ushort* cf1w = canon + coff[14];
    const ushort* cf1b = canon + coff[15];
    const ushort* cf2w = canon + coff[16];
    const ushort* cf2b = canon + coff[17];
    const ushort* cln2g= canon + coff[18];
    const ushort* cln2b= canon + coff[19];

    ushort* xpw_pad = (ushort*)(ws + 6291456);   // [64,512] bf16
    ushort* xz      = (ushort*)(ws + 8388608);   // [8192,1024] bf16, 16 MB (dead after scan)
    float*  y1pre   = (float*)(ws + 8388608);    // [8192,256] f32, 8 MB (reuses xz; becomes y1f)
    ushort* y1b     = (ushort*)(ws + 16777216);  // [8192,256] bf16, 4 MB (reuses xz tail)
    float*  xdbl    = (float*)(ws + 25165824);   // [8192,64] f32, 2 MB
    float*  summh   = (float*)(ws + 27262976);   // [4,128,16,512] f32, 16 MB (dead after scan)
    ushort* h1      = (ushort*)(ws + 27262976);  // [8192,1024] bf16, 16 MB (reuses summh)
    float*  sdtb    = (float*)(ws + 44040192);   // [4,128,512] f32, 1 MB
    ushort* xc      = (ushort*)(ws + 45088768);  // [8192,512] bf16, 8 MB (xi -> yg)
    float*  y2      = (float*)(ws + 45088768);   // [8192,256] f32, 8 MB (reuses xc)
    const ushort* sx = (const ushort*)d_in[0];

    // 1. canon + xpw padding
    canon_k<<<(ctot + 8192 + 255) / 256, 256, 0, stream>>>(ca, canon, xpw_pad, sx);
    // 2. in_proj: xz = x @ ipw^T + ipb; z-half pre-gated (EPI=3); 32x64 tiles,
    //    4096 blocks
    gemm_bt<32, 64, 3, false><<<dim3(256, 16), 256, 0, stream>>>(
        cx, 256, cipw, cipb, nullptr, xz, 1024, 256);
    // 3. conv + silu + xdbl + scan1 (fused; xc write after scan1)
    convscan1_k<<<dim3(128, 4), 512, 0, stream>>>(
        xz, ccw, ccb, xpw_pad, cdtw, cdtb, calog, xc, xdbl, summh, sdtb);
    // 4. combine (128-chunk exclusive prefix)
    combine_k<<<256, 128, 0, stream>>>(summh, sdtb, calog);
    // 5. scan pass 2 (d-split x2) -> yg in-place into xc (gate = 1 multiply)
    scan2_k<<<dim3(128, 2, 4), 256, 0, stream>>>(xz, xc, xdbl, cdtw, cdtb, calog, summh, cdssm);
    // 6. out_proj + cx residual -> y1pre f32 (32x64 tiles, 1024 blocks)
    gemm_bt<32, 64, 2, true><<<dim3(256, 4), 256, 0, stream>>>(
        xc, 512, copw, copb, cx, y1pre, 256, 512);
    // 7. LN1 -> y1b bf16 + y1f f32 (in-place over y1pre)
    ln1_k<<<1024, 512, 0, stream>>>(y1pre, cln1g, cln1b, y1b);
    // 8. fc1 + gelu -> h1 (32x64 tiles, 4096 blocks)
    gemm_bt<32, 64, 1, false><<<dim3(256, 16), 256, 0, stream>>>(
        y1b, 256, cf1w, cf1b, nullptr, h1, 1024, 256);
    // 9. fc2 + gelu -> y2 f32 (32x64 tiles, 1024 blocks, K=1024)
    gemm_bt<32, 64, 1, true><<<dim3(256, 4), 256, 0, stream>>>(
        h1, 1024, cf2w, cf2b, nullptr, y2, 256, 1024);
    // 10. resid + LN2 -> d_out
    ln2_k<<<1024, 512, 0, stream>>>(y2, y1pre, cln2g, cln2b, d_out, sx);
}

// Round 18
// 219.972 us; speedup vs baseline: 1.0196x; 1.0196x over previous
//
#include <hip/hip_runtime.h>

typedef __bf16 bf16x8 __attribute__((ext_vector_type(8)));
typedef float  f32x4  __attribute__((ext_vector_type(4)));

#define AS1 __attribute__((address_space(1)))
#define AS3 __attribute__((address_space(3)))

__device__ __forceinline__ float bf2f(ushort u) {
    union { unsigned int i; float f; } v; v.i = ((unsigned int)u) << 16; return v.f;
}
__device__ __forceinline__ ushort f2bf(float f) {
    union { float f; unsigned int i; } v; v.f = f;
    unsigned int i = v.i;
    unsigned int r = i + 0x7FFFu + ((i >> 16) & 1u);   // RNE
    return (ushort)(r >> 16);
}
__device__ __forceinline__ float bflo(unsigned int u) { return bf2f((ushort)(u & 0xFFFFu)); }
__device__ __forceinline__ float bfhi(unsigned int u) { return bf2f((ushort)(u >> 16)); }
__device__ __forceinline__ float gelu_f(float v) {
    return 0.5f * v * (1.f + erff(v * 0.70710678118654752f));
}

// wave-level inline dtype sniff: 1 = bf16 inputs, 0 = f32
__device__ __forceinline__ bool sniff_inline(const ushort* __restrict__ x) {
    const int lane = threadIdx.x & 63;
    int cnt = 0;
    #pragma unroll
    for (int r = 0; r < 4; r++) {
        const ushort u = x[lane + r * 64];
        const int e = (u >> 7) & 0xFF;
        if ((u & 0x7FFF) == 0 || (e >= 112 && e <= 141)) cnt++;
    }
    #pragma unroll
    for (int o = 32; o > 0; o >>= 1) cnt += __shfl_xor(cnt, o);
    return cnt >= 224;
}

// ---------------------------------------------------------------------------
// canonicalize all inputs into packed bf16 region; also writes xpw_pad [64,512]
// ---------------------------------------------------------------------------
struct CanonArgs {
    const void* src[20];
    int off[20];
    int total;
};

__launch_bounds__(256)
__global__ void canon_k(CanonArgs a, ushort* __restrict__ dst, ushort* __restrict__ xpw_pad,
                        const ushort* __restrict__ sniffx)
{
    const int i = blockIdx.x * 256 + threadIdx.x;
    if (i >= a.total) {
        const int j = i - a.total;
        if (j < 8192) xpw_pad[24576 + j] = 0;   // pad rows 48..63
        return;
    }
    const bool fl = sniff_inline(sniffx);
    int s = 0;
    #pragma unroll
    for (int t = 1; t < 20; t++) if (i >= a.off[t]) s = t;
    const int li = i - a.off[s];
    ushort v;
    if (fl) v = ((const ushort*)a.src[s])[li];
    else    v = f2bf(((const float*)a.src[s])[li]);
    dst[i] = v;
    if (s == 5) xpw_pad[li] = v;                // xpw rows 0..47
}

// ---------------------------------------------------------------------------
// GEMM vs B^T weights, BK=64 single-buffer:
// C[M,N] = A[M,K](lda) @ W[N,K]^T + bias
// EPI: 0 = bias, 1 = bias+gelu, 2 = bias + bf16 residual (stride N),
//      3 = bias, then silu for gn >= 512 (pre-gated z-half for in_proj).
// OUTF: write float instead of bf16.
// LDS XOR-swizzle (chunk ^= row&7, 16B chunks) on both staging source and
// ds_read side keeps the 128B row stride conflict-free. BM in {32,64}.
// ---------------------------------------------------------------------------
template<int BM, int BN, int EPI, bool OUTF>
__launch_bounds__(256, 4)
__global__ void gemm_bt(const ushort* __restrict__ A, int lda, const ushort* __restrict__ W,
                        const ushort* __restrict__ bias, const ushort* __restrict__ resid,
                        void* __restrict__ Cb, int N, int K)
{
    constexpr int WNT = BN / 32;
    __shared__ __align__(16) ushort As[BM * 64];
    __shared__ __align__(16) ushort Bs[BN * 64];
    const int tid  = threadIdx.x;
    const int wave = tid >> 6;
    const int lane = tid & 63;
    const int m0 = blockIdx.x * BM;
    const int n0 = blockIdx.y * BN;
    const int wm = (wave >> 1) * (BM / 2);
    const int wn = (wave & 1) * (BN / 2);
    const int lrow = lane & 15;
    const int quad = lane >> 4;
    // staging decomposition: 8 lanes per 64-elem row, 8 rows per inst
    const int rsub = lane >> 3;                    // 0..7 (row within inst)
    const int ksub = (lane & 7) ^ rsub;            // swizzled k-chunk for linear LDS dest

    constexpr int WMR = (BM == 32) ? 1 : BM / 32;  // row-fragment repeats per wave
    f32x4 acc[WMR][WNT];
    #pragma unroll
    for (int i = 0; i < WMR; i++)
        #pragma unroll
        for (int j = 0; j < WNT; j++)
            #pragma unroll
            for (int r = 0; r < 4; r++) acc[i][j][r] = 0.f;

    for (int k0 = 0; k0 < K; k0 += 64) {
        #pragma unroll
        for (int t = 0; t < BM / 32; t++) {        // A insts = BM/8, /4 waves
            const int inst = t * 4 + wave;
            const int row  = inst * 8 + rsub;
            const ushort* gp = A + (size_t)(m0 + row) * lda + (k0 + ksub * 8);
            __builtin_amdgcn_global_load_lds((AS1 void*)(void*)gp,
                                             (AS3 void*)(As + inst * 512), 16, 0, 0);
        }
        #pragma unroll
        for (int t = 0; t < BN / 32; t++) {        // B insts = BN/8, /4 waves
            const int inst = t * 4 + wave;
            const int row  = inst * 8 + rsub;
            const ushort* gp = W + (size_t)(n0 + row) * K + (k0 + ksub * 8);
            __builtin_amdgcn_global_load_lds((AS1 void*)(void*)gp,
                                             (AS3 void*)(Bs + inst * 512), 16, 0, 0);
        }
        __syncthreads();
        #pragma unroll
        for (int kk = 0; kk < 64; kk += 32) {
            bf16x8 afr[WMR], bfr[WNT];
            #pragma unroll
            for (int i = 0; i < WMR; i++) {
                const int r = wm + i * 16 + lrow;
                const int ch = (kk >> 3) + quad;
                afr[i] = *(const bf16x8*)&As[r * 64 + ((ch ^ (r & 7)) << 3)];
            }
            #pragma unroll
            for (int j = 0; j < WNT; j++) {
                const int r = wn + j * 16 + lrow;
                const int ch = (kk >> 3) + quad;
                bfr[j] = *(const bf16x8*)&Bs[r * 64 + ((ch ^ (r & 7)) << 3)];
            }
            #pragma unroll
            for (int i = 0; i < WMR; i++)
                #pragma unroll
                for (int j = 0; j < WNT; j++)
                    acc[i][j] = __builtin_amdgcn_mfma_f32_16x16x32_bf16(afr[i], bfr[j], acc[i][j], 0, 0, 0);
        }
        __syncthreads();
    }

    #pragma unroll
    for (int i = 0; i < WMR; i++) {
        const int gm = m0 + wm + i * 16 + quad * 4;
        #pragma unroll
        for (int j = 0; j < WNT; j++) {
            const int gn = n0 + wn + j * 16 + lrow;
            const float bv = bf2f(bias[gn]);
            #pragma unroll
            for (int r = 0; r < 4; r++) {
                float v = acc[i][j][r] + bv;
                if (EPI == 1) v = gelu_f(v);
                if (EPI == 2) v += bf2f(resid[(size_t)(gm + r) * N + gn]);
                if (EPI == 3) { if (gn >= 512) v = v / (1.f + __expf(-v)); }
                if (OUTF) ((float*)Cb)[(size_t)(gm + r) * N + gn] = v;
                else      ((ushort*)Cb)[(size_t)(gm + r) * N + gn] = f2bf(v);
            }
        }
    }
}

// ---------------------------------------------------------------------------
// LN1: row-LN over 256 cols of y1pre (f32); writes y1b bf16 + y1f f32
// (y1f in-place over y1pre). grid 1024 x 512.
// ---------------------------------------------------------------------------
__launch_bounds__(512)
__global__ void ln1_k(float* __restrict__ y1pre, const ushort* __restrict__ g1,
                      const ushort* __restrict__ b1, ushort* __restrict__ y1b)
{
    const int tid  = threadIdx.x;
    const int wave = tid >> 6;
    const int lane = tid & 63;
    const int row  = blockIdx.x * 8 + wave;
    const int col0 = lane * 4;

    const f32x4 a = *(const f32x4*)&y1pre[(size_t)row * 256 + col0];
    float S = 0.f, Q = 0.f;
    #pragma unroll
    for (int k = 0; k < 4; k++) { S += a[k]; Q += a[k] * a[k]; }
    #pragma unroll
    for (int o = 32; o > 0; o >>= 1) {
        S += __shfl_xor(S, o);
        Q += __shfl_xor(Q, o);
    }
    const float mean = S * (1.f / 256.f);
    const float var  = Q * (1.f / 256.f) - mean * mean;
    const float rs   = rsqrtf(var + 1e-5f);

    float of[4];
    ushort ob[4];
    #pragma unroll
    for (int k = 0; k < 4; k++) {
        of[k] = (a[k] - mean) * rs * bf2f(g1[col0 + k]) + bf2f(b1[col0 + k]);
        ob[k] = f2bf(of[k]);
    }
    *(f32x4*)&y1pre[(size_t)row * 256 + col0] = *(f32x4*)&of[0];   // y1f in-place
    *(ushort4*)&y1b[(size_t)row * 256 + col0] = *(ushort4*)&ob[0];
}

// ---------------------------------------------------------------------------
// FUSED conv+SiLU + xdbl projection + scan pass 1. grid (128c, 4b) x 512.
// xc global write after scan1 (stores retire in kernel-end drain).
// ---------------------------------------------------------------------------
__launch_bounds__(512, 2)
__global__ void convscan1_k(const ushort* __restrict__ xz, const ushort* __restrict__ cw,
                            const ushort* __restrict__ cb, const ushort* __restrict__ xpw_pad,
                            const ushort* __restrict__ dtw, const ushort* __restrict__ dtb,
                            const ushort* __restrict__ Alog,
                            ushort* __restrict__ xc, float* __restrict__ xdbl,
                            float* __restrict__ summh, float* __restrict__ sdtb)
{
    __shared__ __align__(16) ushort xcs[16 * 520];
    __shared__ float XD[16 * 48];
    const int tid  = threadIdx.x;
    const int wave = tid >> 6;
    const int lane = tid & 63;
    const int lrow = lane & 15;
    const int quad = lane >> 4;
    const int c = blockIdx.x, b = blockIdx.y;
    const int t0 = b * 2048 + c * 16;

    // ---- conv + silu -> xcs ----
    {
        const int d8 = (tid & 63) * 8;
        ushort wl[32];
        *(uint4*)&wl[0]  = *(const uint4*)&cw[d8 * 4];
        *(uint4*)&wl[8]  = *(const uint4*)&cw[d8 * 4 + 8];
        *(uint4*)&wl[16] = *(const uint4*)&cw[d8 * 4 + 16];
        *(uint4*)&wl[24] = *(const uint4*)&cw[d8 * 4 + 24];
        ushort bl[8];
        *(uint4*)&bl[0] = *(const uint4*)&cb[d8];
        #pragma unroll
        for (int it = 0; it < 2; it++) {
            const int trow = it * 8 + wave;
            const int t = t0 + trow;
            const int l = t & 2047;
            float acc[8];
            #pragma unroll
            for (int j = 0; j < 8; j++) acc[j] = bf2f(bl[j]);
            #pragma unroll
            for (int k = 0; k < 4; k++) {
                const int ls = l - 3 + k;
                if (ls >= 0) {
                    ushort xl[8];
                    *(uint4*)&xl[0] = *(const uint4*)&xz[(size_t)(t - 3 + k) * 1024 + d8];
                    #pragma unroll
                    for (int j = 0; j < 8; j++) acc[j] += bf2f(xl[j]) * bf2f(wl[j * 4 + k]);
                }
            }
            ushort ol[8];
            #pragma unroll
            for (int j = 0; j < 8; j++) {
                const float s = acc[j] / (1.f + __expf(-acc[j]));
                ol[j] = f2bf(s);
            }
            *(uint4*)&xcs[trow * 520 + d8] = *(uint4*)&ol[0];
        }
    }
    __syncthreads();

    // ---- xdbl = xcs @ xpw_pad^T: M=16, N=48, K=512; waves 0..2 fill XD ----
    if (wave < 3) {
        const int nt = wave;
        const ushort* bptr = xpw_pad + (size_t)(nt * 16 + lrow) * 512 + quad * 8;
        f32x4 acc = {0.f, 0.f, 0.f, 0.f};
        #pragma unroll
        for (int hh = 0; hh < 2; hh++) {
            bf16x8 Bv[8];
            #pragma unroll
            for (int s = 0; s < 8; s++)
                Bv[s] = *(const bf16x8*)(bptr + hh * 256 + s * 32);
            #pragma unroll
            for (int s = 0; s < 8; s++) {
                const bf16x8 afr = *(const bf16x8*)&xcs[lrow * 520 + hh * 256 + s * 32 + quad * 8];
                acc = __builtin_amdgcn_mfma_f32_16x16x32_bf16(afr, Bv[s], acc, 0, 0, 0);
            }
        }
        const int col = nt * 16 + lrow;
        if (col < 48) {
            #pragma unroll
            for (int r = 0; r < 4; r++) {
                const int row = quad * 4 + r;
                XD[row * 48 + col] = acc[r];
                xdbl[(size_t)(t0 + row) * 64 + col] = acc[r];
            }
        }
    }
    __syncthreads();

    // ---- scan pass 1: thread owns d = tid; xi and XD from LDS ----
    {
        const int d = tid;
        const uint4 w0 = *(const uint4*)&dtw[d * 16];
        const uint4 w1 = *(const uint4*)&dtw[d * 16 + 8];
        const float wd[16] = { bflo(w0.x), bfhi(w0.x), bflo(w0.y), bfhi(w0.y),
                               bflo(w0.z), bfhi(w0.z), bflo(w0.w), bfhi(w0.w),
                               bflo(w1.x), bfhi(w1.x), bflo(w1.y), bfhi(w1.y),
                               bflo(w1.z), bfhi(w1.z), bflo(w1.w), bfhi(w1.w) };
        const uint4 a0 = *(const uint4*)&Alog[d * 16];
        const uint4 a1 = *(const uint4*)&Alog[d * 16 + 8];
        const float al[16] = { bflo(a0.x), bfhi(a0.x), bflo(a0.y), bfhi(a0.y),
                               bflo(a0.z), bfhi(a0.z), bflo(a0.w), bfhi(a0.w),
                               bflo(a1.x), bfhi(a1.x), bflo(a1.y), bfhi(a1.y),
                               bflo(a1.z), bfhi(a1.z), bflo(a1.w), bfhi(a1.w) };
        const float dtbv = bf2f(dtb[d]);
        float A[16], h[16];
        #pragma unroll
        for (int n = 0; n < 16; n++) { A[n] = -__expf(al[n]); h[n] = 0.f; }
        float sdt = 0.f;
        for (int i = 0; i < 16; i++) {
            const float* Xr = &XD[i * 48];
            float s0 = dtbv, s1 = 0.f, s2 = 0.f, s3 = 0.f;
            #pragma unroll
            for (int k = 0; k < 16; k += 4) {
                s0 += Xr[k]     * wd[k];
                s1 += Xr[k + 1] * wd[k + 1];
                s2 += Xr[k + 2] * wd[k + 2];
                s3 += Xr[k + 3] * wd[k + 3];
            }
            const float s = (s0 + s1) + (s2 + s3);
            const float dtv = (s > 15.f) ? s : __logf(1.f + __expf(s));
            const float xiv = bf2f(xcs[i * 520 + d]);
            const float dx = dtv * xiv;
            sdt += dtv;
            #pragma unroll
            for (int n = 0; n < 16; n++) {
                const float da = __expf(dtv * A[n]);
                h[n] = da * h[n] + dx * Xr[16 + n];
            }
        }
        const size_t bh = ((size_t)(b * 128 + c) * 16) * 512 + d;
        #pragma unroll
        for (int n = 0; n < 16; n++) summh[bh + (size_t)n * 512] = h[n];
        sdtb[(size_t)(b * 128 + c) * 512 + d] = sdt;
    }

    // ---- write xc to global (after scan1; retires in kernel-end drain) ----
    {
        const int row = tid >> 5;
        const int col = (tid & 31) * 16;
        *(uint4*)&xc[(size_t)(t0 + row) * 512 + col]     = *(const uint4*)&xcs[row * 520 + col];
        *(uint4*)&xc[(size_t)(t0 + row) * 512 + col + 8] = *(const uint4*)&xcs[row * 520 + col + 8];
    }
}

// sequential combine over 128 chunks; recomputes decay p = exp(A[n]*sdt);
// overwrites h-slot with exclusive-prefix h_in. grid 256 x 128 (b,n,dq).
__launch_bounds__(128)
__global__ void combine_k(float* __restrict__ summh, const float* __restrict__ sdtb,
                          const ushort* __restrict__ Alog)
{
    const int b  = blockIdx.x >> 6;
    const int n  = (blockIdx.x >> 2) & 15;
    const int dq = blockIdx.x & 3;
    const int d  = dq * 128 + threadIdx.x;
    const float An = -__expf(bf2f(Alog[d * 16 + n]));
    float h = 0.f;
    #pragma unroll
    for (int q = 0; q < 4; q++) {
        float p[32], hl[32], ho[32];
        #pragma unroll
        for (int c2 = 0; c2 < 32; c2++) {
            const int cc = q * 32 + c2;
            hl[c2] = summh[((size_t)(b * 128 + cc) * 16 + n) * 512 + d];
            p[c2]  = __expf(An * sdtb[(size_t)(b * 128 + cc) * 512 + d]);
        }
        #pragma unroll
        for (int c2 = 0; c2 < 32; c2++) {
            ho[c2] = h;
            h = p[c2] * h + hl[c2];
        }
        #pragma unroll
        for (int c2 = 0; c2 < 32; c2++)
            summh[((size_t)(b * 128 + (q * 32 + c2)) * 16 + n) * 512 + d] = ho[c2];
    }
}

// ---------------------------------------------------------------------------
// scan pass 2: 16-token chunks, d-split x2. grid (128c, 2dh, 4b) x 256.
// reads h_in from summh; z-half of xz is PRE-GATED (silu applied by in_proj)
// so the gate is a single multiply; writes gated y IN-PLACE into xc.
// ---------------------------------------------------------------------------
__launch_bounds__(256)
__global__ void scan2_k(const ushort* __restrict__ xz, ushort* __restrict__ xc,
                        const float* __restrict__ xdbl,
                        const ushort* __restrict__ dtw, const ushort* __restrict__ dtb,
                        const ushort* __restrict__ Alog, const float* __restrict__ summh,
                        const ushort* __restrict__ Dssm)
{
    __shared__ float XD[16 * 48];
    const int tid = threadIdx.x;
    const int c = blockIdx.x, dh = blockIdx.y, b = blockIdx.z;
    const int t0 = b * 2048 + c * 16;
    const int d = dh * 256 + tid;

    for (int e = tid; e < 768; e += 256)
        XD[e] = xdbl[(size_t)(t0 + (e / 48)) * 64 + (e % 48)];
    __syncthreads();

    const uint4 w0 = *(const uint4*)&dtw[d * 16];
    const uint4 w1 = *(const uint4*)&dtw[d * 16 + 8];
    const float wd[16] = { bflo(w0.x), bfhi(w0.x), bflo(w0.y), bfhi(w0.y),
                           bflo(w0.z), bfhi(w0.z), bflo(w0.w), bfhi(w0.w),
                           bflo(w1.x), bfhi(w1.x), bflo(w1.y), bfhi(w1.y),
                           bflo(w1.z), bfhi(w1.z), bflo(w1.w), bfhi(w1.w) };
    const uint4 a0 = *(const uint4*)&Alog[d * 16];
    const uint4 a1 = *(const uint4*)&Alog[d * 16 + 8];
    const float al[16] = { bflo(a0.x), bfhi(a0.x), bflo(a0.y), bfhi(a0.y),
                           bflo(a0.z), bfhi(a0.z), bflo(a0.w), bfhi(a0.w),
                           bflo(a1.x), bfhi(a1.x), bflo(a1.y), bfhi(a1.y),
                           bflo(a1.z), bfhi(a1.z), bflo(a1.w), bfhi(a1.w) };
    const float dtbv = bf2f(dtb[d]);
    float A[16], h[16];
    #pragma unroll
    for (int n = 0; n < 16; n++) A[n] = -__expf(al[n]);
    const size_t bh = ((size_t)(b * 128 + c) * 16) * 512 + d;
    #pragma unroll
    for (int n = 0; n < 16; n++) h[n] = summh[bh + (size_t)n * 512];
    const float Dv = bf2f(Dssm[d]);

    for (int i = 0; i < 16; i++) {
        const int t = t0 + i;
        const float* Xr = &XD[i * 48];
        float s0 = dtbv, s1 = 0.f, s2 = 0.f, s3 = 0.f;
        #pragma unroll
        for (int k = 0; k < 16; k += 4) {
            s0 += Xr[k]     * wd[k];
            s1 += Xr[k + 1] * wd[k + 1];
            s2 += Xr[k + 2] * wd[k + 2];
            s3 += Xr[k + 3] * wd[k + 3];
        }
        const float s = (s0 + s1) + (s2 + s3);
        const float dtv = (s > 15.f) ? s : __logf(1.f + __expf(s));
        const float xiv = bf2f(xc[(size_t)t * 512 + d]);
        const float dx = dtv * xiv;
        float yv0 = 0.f, yv1 = 0.f;
        #pragma unroll
        for (int n = 0; n < 16; n += 2) {
            const float da0 = __expf(dtv * A[n]);
            const float da1 = __expf(dtv * A[n + 1]);
            h[n]     = da0 * h[n]     + dx * Xr[16 + n];
            h[n + 1] = da1 * h[n + 1] + dx * Xr[17 + n];
            yv0 += h[n]     * Xr[32 + n];
            yv1 += h[n + 1] * Xr[33 + n];
        }
        float yv = yv0 + yv1;
        yv += xiv * Dv;
        yv *= bf2f(xz[(size_t)t * 1024 + 512 + d]);   // z pre-gated (silu in in_proj)
        xc[(size_t)t * 512 + d] = f2bf(yv);   // in-place: yg overwrites xi
    }
}

// ---------------------------------------------------------------------------
// final LN2: v = y2g + y1f (gelu already applied by fc2); row-LN over 256;
// dtype-sniffed output.
// ---------------------------------------------------------------------------
__launch_bounds__(512)
__global__ void ln2_k(const float* __restrict__ y2, const float* __restrict__ y1f,
                      const ushort* __restrict__ g2, const ushort* __restrict__ b2,
                      void* __restrict__ dout, const ushort* __restrict__ sniffx)
{
    const int tid  = threadIdx.x;
    const int wave = tid >> 6;
    const int lane = tid & 63;
    const int row  = blockIdx.x * 8 + wave;
    const int col0 = lane * 4;

    const f32x4 a = *(const f32x4*)&y2[(size_t)row * 256 + col0];
    const f32x4 rsd = *(const f32x4*)&y1f[(size_t)row * 256 + col0];
    float v[4];
    float S = 0.f, Q = 0.f;
    #pragma unroll
    for (int k = 0; k < 4; k++) {
        v[k] = a[k] + rsd[k];
        S += v[k];
        Q += v[k] * v[k];
    }
    #pragma unroll
    for (int o = 32; o > 0; o >>= 1) {
        S += __shfl_xor(S, o);
        Q += __shfl_xor(Q, o);
    }
    const float mean = S * (1.f / 256.f);
    const float var  = Q * (1.f / 256.f) - mean * mean;
    const float rs   = rsqrtf(var + 1e-5f);

    const bool fl = sniff_inline(sniffx);
    if (fl) {
        ushort o4[4];
        #pragma unroll
        for (int k = 0; k < 4; k++)
            o4[k] = f2bf((v[k] - mean) * rs * bf2f(g2[col0 + k]) + bf2f(b2[col0 + k]));
        *(ushort4*)((ushort*)dout + (size_t)row * 256 + col0) = *(ushort4*)&o4[0];
    } else {
        float o4[4];
        #pragma unroll
        for (int k = 0; k < 4; k++)
            o4[k] = (v[k] - mean) * rs * bf2f(g2[col0 + k]) + bf2f(b2[col0 + k]);
        *(float4*)((float*)dout + (size_t)row * 256 + col0) = *(float4*)&o4[0];
    }
}

// ---------------------------------------------------------------------------
extern "C" void kernel_launch(void* const* d_in, const int* in_sizes, int n_in,
                              void* d_out, int out_size, void* d_ws, size_t ws_size,
                              hipStream_t stream)
{
    char* ws = (char*)d_ws;
    ushort* canon = (ushort*)(ws + 256);

    static const int coff[20] = {
        0,        2097152,  2359296,  2360320,  2362368,
        2362880,  2387456,  2395648,  2396160,  2404352,
        2404864,  2535936,  2536192,  2536448,  2536704,
        2798848,  2799872,  3062016,  3062272,  3062528 };
    static const int ctot = 3062784;

    CanonArgs ca;
    for (int i = 0; i < 20; i++) { ca.src[i] = d_in[i]; ca.off[i] = coff[i]; }
    ca.total = ctot;

    const ushort* cx   = canon + coff[0];
    const ushort* cipw = canon + coff[1];
    const ushort* cipb = canon + coff[2];
    const ushort* ccw  = canon + coff[3];
    const ushort* ccb  = canon + coff[4];
    const ushort* cdtw = canon + coff[6];
    const ushort* cdtb = canon + coff[7];
    const ushort* calog= canon + coff[8];
    const ushort* cdssm= canon + coff[9];
    const ushort* copw = canon + coff[10];
    const ushort* copb = canon + coff[11];
    const ushort* cln1g= canon + coff[12];
    const ushort* cln1b= canon + coff[13];
    const ushort* cf1w = canon + coff[14];
    const ushort* cf1b = canon + coff[15];
    const ushort* cf2w = canon + coff[16];
    const ushort* cf2b = canon + coff[17];
    const ushort* cln2g= canon + coff[18];
    const ushort* cln2b= canon + coff[19];

    ushort* xpw_pad = (ushort*)(ws + 6291456);   // [64,512] bf16
    ushort* xz      = (ushort*)(ws + 8388608);   // [8192,1024] bf16, 16 MB (dead after scan)
    float*  y1pre   = (float*)(ws + 8388608);    // [8192,256] f32, 8 MB (reuses xz; becomes y1f)
    ushort* y1b     = (ushort*)(ws + 16777216);  // [8192,256] bf16, 4 MB (reuses xz tail)
    float*  xdbl    = (float*)(ws + 25165824);   // [8192,64] f32, 2 MB
    float*  summh   = (float*)(ws + 27262976);   // [4,128,16,512] f32, 16 MB (dead after scan)
    ushort* h1      = (ushort*)(ws + 27262976);  // [8192,1024] bf16, 16 MB (reuses summh)
    float*  sdtb    = (float*)(ws + 44040192);   // [4,128,512] f32, 1 MB
    ushort* xc      = (ushort*)(ws + 45088768);  // [8192,512] bf16, 8 MB (xi -> yg)
    float*  y2      = (float*)(ws + 45088768);   // [8192,256] f32, 8 MB (reuses xc)
    const ushort* sx = (const ushort*)d_in[0];

    // 1. canon + xpw padding
    canon_k<<<(ctot + 8192 + 255) / 256, 256, 0, stream>>>(ca, canon, xpw_pad, sx);
    // 2. in_proj: xz = x @ ipw^T + ipb; z-half pre-gated (EPI=3); 64x64 tiles,
    //    2048 blocks
    gemm_bt<64, 64, 3, false><<<dim3(128, 16), 256, 0, stream>>>(
        cx, 256, cipw, cipb, nullptr, xz, 1024, 256);
    // 3. conv + silu + xdbl + scan1 (fused; xc write after scan1)
    convscan1_k<<<dim3(128, 4), 512, 0, stream>>>(
        xz, ccw, ccb, xpw_pad, cdtw, cdtb, calog, xc, xdbl, summh, sdtb);
    // 4. combine (128-chunk exclusive prefix)
    combine_k<<<256, 128, 0, stream>>>(summh, sdtb, calog);
    // 5. scan pass 2 (d-split x2) -> yg in-place into xc (gate = 1 multiply)
    scan2_k<<<dim3(128, 2, 4), 256, 0, stream>>>(xz, xc, xdbl, cdtw, cdtb, calog, summh, cdssm);
    // 6. out_proj + cx residual -> y1pre f32 (32x64 tiles, 1024 blocks)
    gemm_bt<32, 64, 2, true><<<dim3(256, 4), 256, 0, stream>>>(
        xc, 512, copw, copb, cx, y1pre, 256, 512);
    // 7. LN1 -> y1b bf16 + y1f f32 (in-place over y1pre)
    ln1_k<<<1024, 512, 0, stream>>>(y1pre, cln1g, cln1b, y1b);
    // 8. fc1 + gelu -> h1 (64x64 tiles, 2048 blocks)
    gemm_bt<64, 64, 1, false><<<dim3(128, 16), 256, 0, stream>>>(
        y1b, 256, cf1w, cf1b, nullptr, h1, 1024, 256);
    // 9. fc2 + gelu -> y2 f32 (32x64 tiles, 1024 blocks, K=1024)
    gemm_bt<32, 64, 1, true><<<dim3(256, 4), 256, 0, stream>>>(
        h1, 1024, cf2w, cf2b, nullptr, y2, 256, 1024);
    // 10. resid + LN2 -> d_out
    ln2_k<<<1024, 512, 0, stream>>>(y2, y1pre, cln2g, cln2b, d_out, sx);
}